// Round 10
// baseline (228.933 us; speedup 1.0000x reference)
//
#include <hip/hip_runtime.h>
#include <cstdint>

#define LDP 136          // padded LDS row stride in bf16 elems (272B, 16B-aligned)
#define INFV 3.0e38f
#define CB_STRIDE 147840 // padded diag-major cost elems per batch

typedef short bf16x8 __attribute__((ext_vector_type(8)));
typedef float f32x4  __attribute__((ext_vector_type(4)));

__device__ inline float bf2f(uint32_t bits){
  return __builtin_bit_cast(float, bits << 16);
}
__device__ inline float bf2f_lo(uint32_t w){ return __builtin_bit_cast(float, w << 16); }
__device__ inline float bf2f_hi(uint32_t w){ return __builtin_bit_cast(float, w & 0xffff0000u); }
__device__ inline ushort f2bf(float f){
  uint32_t u = __builtin_bit_cast(uint32_t, f);
  u += 0x7fffu + ((u >> 16) & 1u);   // round-to-nearest-even
  return (ushort)(u >> 16);
}

// ---- DPP helper: VALU cross-lane ------------------------------------------
#define DPPF(x, oldv, ctrl) \
  __builtin_bit_cast(float, __builtin_amdgcn_update_dpp( \
      __builtin_bit_cast(int,(oldv)), __builtin_bit_cast(int,(x)), \
      (ctrl), 0xf, 0xf, false))

__device__ inline float rl(float v, int l){    // readlane (uniform, VALU)
  return __builtin_bit_cast(float, __builtin_amdgcn_readlane(__builtin_bit_cast(int, v), l));
}

// diag-major compact offset of cell (i,j), even-padded per diag so every
// diag's absolute-j byte base is 4B-aligned. Verified R7/R8 (absmax 0).
__device__ inline int diag_off(int i, int j){
  const int d = i + j;
  if (d <= 383){
    return ((d*(d+1))>>1) + ((d+1)>>1) + j;
  } else {
    const int e2 = 767 - d;
    return 147456 - ((e2*(e2+1))>>1) + 193 + ((d-384)>>1) + j - (d-383);
  }
}

// ---------------------------------------------------------------------------
// Kernel 1: cost GEMM (bf16 MFMA) with diag-major epilogue stores.
// (unchanged — refcheck'd R7/R8)
// ---------------------------------------------------------------------------
__global__ __launch_bounds__(256) void dtw_cost_gemm(
    const float* __restrict__ s1, const float* __restrict__ s2,
    ushort* __restrict__ cost)
{
  __shared__ ushort As[128*LDP];
  __shared__ ushort Bs[128*LDP];
  __shared__ float  n1s[128];
  __shared__ float  n2s[128];

  const int b  = blockIdx.y;
  const int ti = blockIdx.x / 3;
  const int tj = blockIdx.x % 3;
  const int t  = threadIdx.x;

  {
    const int row = t >> 1;
    const int par = t & 1;
    const float* Arow = s1 + ((size_t)(b*384 + ti*128 + row)) * 128;
    const float* Brow = s2 + ((size_t)(b*384 + tj*128 + row)) * 128;
    ushort* Asr = As + row*LDP;
    ushort* Bsr = Bs + row*LDP;
#pragma unroll
    for (int q = 0; q < 16; q++){
      const int col = ((2*q + par + 15*row) & 31) * 4;
      float4 va = *(const float4*)(Arow + col);
      float4 vb = *(const float4*)(Brow + col);
      ushort4 ua = make_ushort4(f2bf(va.x), f2bf(va.y), f2bf(va.z), f2bf(va.w));
      ushort4 ub = make_ushort4(f2bf(vb.x), f2bf(vb.y), f2bf(vb.z), f2bf(vb.w));
      *(ushort4*)(Asr + col) = ua;
      *(ushort4*)(Bsr + col) = ub;
    }
  }
  __syncthreads();

  {
    const ushort* rowp = (t < 128) ? (As + t*LDP) : (Bs + (t-128)*LDP);
    float s = 0.0f;
#pragma unroll
    for (int e = 0; e < 128; e += 8){
      bf16x8 v = *(const bf16x8*)(rowp + e);
#pragma unroll
      for (int k = 0; k < 8; k++){
        float f = bf2f((uint16_t)v[k]);
        s += f*f;
      }
    }
    if (t < 128) n1s[t] = s; else n2s[t-128] = s;
  }
  __syncthreads();

  const int lane = t & 63;
  const int wid  = t >> 6;
  const int wr = wid >> 1, wc = wid & 1;
  const int lrow = lane & 15;
  const int lk   = lane >> 4;

  f32x4 acc[4][4] = {};
#pragma unroll
  for (int kk = 0; kk < 4; kk++){
    const int kb = kk*32 + lk*8;
    bf16x8 af[4], bfv[4];
#pragma unroll
    for (int f = 0; f < 4; f++){
      af[f]  = *(const bf16x8*)(As + (wr*64 + f*16 + lrow)*LDP + kb);
      bfv[f] = *(const bf16x8*)(Bs + (wc*64 + f*16 + lrow)*LDP + kb);
    }
#pragma unroll
    for (int i = 0; i < 4; i++)
#pragma unroll
      for (int j = 0; j < 4; j++)
        acc[i][j] = __builtin_amdgcn_mfma_f32_16x16x32_bf16(af[i], bfv[j], acc[i][j], 0, 0, 0);
  }

  ushort* Cb = cost + (size_t)b * CB_STRIDE;
  const int i0 = ti*128 + wr*64;
  const int j0 = tj*128 + wc*64;
  float n2v[4];
#pragma unroll
  for (int fj = 0; fj < 4; fj++) n2v[fj] = n2s[wc*64 + fj*16 + lrow];
#pragma unroll
  for (int fi = 0; fi < 4; fi++){
#pragma unroll
    for (int r = 0; r < 4; r++){
      const int il = wr*64 + fi*16 + lk*4 + r;
      const int i  = i0 + fi*16 + lk*4 + r;
      const float n1v = n1s[il];
#pragma unroll
      for (int fj = 0; fj < 4; fj++){
        float cv = n1v + n2v[fj] - 2.0f*acc[fi][fj][r];
        const int col = j0 + fj*16 + lrow;
        Cb[diag_off(i, col)] = f2bf(cv);
      }
    }
  }
}

// ---------------------------------------------------------------------------
// Kernel 2: DTW DP — anti-diagonal wavefront over diag-major cost, staged
// via global_load_lds in GROUPS of 8 diags (one 16B DMA per diag), ring of
// 4 group-slots (32 KiB), ONE counted vmcnt fence per group. Inside a group
// everything is plain (ds_read + VALU) so the compiler overlaps the 8 steps;
// only the ~3-op/diag serial chain remains exposed.
// ---------------------------------------------------------------------------
__global__ __launch_bounds__(64, 1) void dtw_dp(
    const ushort* __restrict__ cost, float* __restrict__ partial)
{
  __shared__ uint32_t lds[4*8*256];   // 4 group-slots x 8 diags x 256 dwords
  const int b    = blockIdx.x;
  const int lane = threadIdx.x;
  const ushort* Cp = cost + (size_t)b * CB_STRIDE;

  typedef __attribute__((address_space(1))) const uint32_t GU32;
  typedef __attribute__((address_space(3))) uint32_t LU32;

  // ---- seed first (plain load; compiler's own vmcnt lands before any DMA)
  float a0 = (lane == 0) ? bf2f((uint32_t)Cp[0]) : INFV;   // D(0)
  float a1=INFV,a2=INFV,a3=INFV,a4=INFV,a5=INFV;
  float b0=INFV,b1=INFV,b2=INFV,b3=INFV,b4=INFV,b5=INFV;   // D(-1)
  float sa=INFV, sb=INFV;

  int pds = 1, bbs = 4;   // stage-side: next diag to stage, its byte base
  int pdc = 1, bbc = 4;   // consume-side

  // advance (pd, bb) to the next diag (byte-base deltas verified R7/R8)
#define ADVX(pd, bb) do{ \
    int adv_ = ((pd) < 383) ? ((pd) + 1 + (((pd) & 1) ^ 1)) \
             : (((pd) == 383) ? 384 : ((767 - (pd)) + ((pd) & 1) - 1)); \
    (bb) += 2*adv_; (pd)++; \
  } while(0)

  // stage one diag: 16B/lane DMA from (base&~15)+16*lane; clamp keeps the
  // 1024B window inside the batch; remainder handled by the read offset.
#define SSTEP(SLOTB) do{ \
    int gb_ = bbs < 294656 ? bbs : 294656; gb_ &= ~15; \
    const char* gp_ = (const char*)Cp + gb_ + 16*lane; \
    __builtin_amdgcn_global_load_lds((GU32*)gp_, (LU32*)&lds[SLOTB], 16, 0, 0); \
    ADVX(pds, bbs); \
  } while(0)

#define WAITV(n) do { \
    asm volatile("s_waitcnt vmcnt(" #n ")" ::: "memory"); \
    __builtin_amdgcn_sched_barrier(0); \
  } while(0)

  // recurrence body (proven R7): n = c + min3(p, sh(p), sh(q)/q); q <- n
#define BODYP(W0,W1,W2, p0,p1,p2,p3,p4,p5, q0,q1,q2,q3,q4,q5, shp, shq) do{ \
    float c0=bf2f_lo(W0), c1=bf2f_hi(W0), c2=bf2f_lo(W1), \
          c3=bf2f_hi(W1), c4=bf2f_lo(W2), c5=bf2f_hi(W2); \
    float n0 = c0 + fminf(fminf(p0, shp), shq); \
    float n1 = c1 + fminf(fminf(p1, p0), q0); \
    float n2 = c2 + fminf(fminf(p2, p1), q1); \
    float n3 = c3 + fminf(fminf(p3, p2), q2); \
    float n4 = c4 + fminf(fminf(p4, p3), q3); \
    float n5 = c5 + fminf(fminf(p5, p4), q4); \
    float sh_ = DPPF(n5, INFV, 0x111); \
    sh_ = (lane==16) ? rl(n5,15) : sh_; \
    sh_ = (lane==32) ? rl(n5,31) : sh_; \
    sh_ = (lane==48) ? rl(n5,47) : sh_; \
    q0=n0; q1=n1; q2=n2; q3=n3; q4=n4; q5=n5; \
    shq = sh_; \
  } while(0)

#define CSTEP_AB(SLOTB) do{ \
    int gb_ = bbc < 294656 ? bbc : 294656; gb_ &= ~15; \
    int ix_ = (SLOTB) + ((bbc - gb_) >> 2) + 3*lane; \
    uint32_t W0_=lds[ix_], W1_=lds[ix_+1], W2_=lds[ix_+2]; \
    ADVX(pdc, bbc); \
    BODYP(W0_,W1_,W2_, a0,a1,a2,a3,a4,a5, b0,b1,b2,b3,b4,b5, sa, sb); \
  } while(0)
#define CSTEP_BA(SLOTB) do{ \
    int gb_ = bbc < 294656 ? bbc : 294656; gb_ &= ~15; \
    int ix_ = (SLOTB) + ((bbc - gb_) >> 2) + 3*lane; \
    uint32_t W0_=lds[ix_], W1_=lds[ix_+1], W2_=lds[ix_+2]; \
    ADVX(pdc, bbc); \
    BODYP(W0_,W1_,W2_, b0,b1,b2,b3,b4,b5, a0,a1,a2,a3,a4,a5, sb, sa); \
  } while(0)

  // ---- prologue: stage groups 0..2 (diags 1..24) into slots 0..2 ----
  for (int s = 0; s < 3; ++s)
    for (int t = 0; t < 8; ++t)
      SSTEP((s*8 + t)*256);

  // ---- main: groups 0..93 consume diags 1..752; stage g+3 (<=95) ----
  for (int g = 0; g < 94; ++g){
    WAITV(16);
    const int gb = (g & 3) * 2048;
    CSTEP_AB(gb+   0); CSTEP_BA(gb+ 256);
    CSTEP_AB(gb+ 512); CSTEP_BA(gb+ 768);
    CSTEP_AB(gb+1024); CSTEP_BA(gb+1280);
    CSTEP_AB(gb+1536); CSTEP_BA(gb+1792);
    if (g < 93){
      const int sbb = ((g+3) & 3) * 2048;
      SSTEP(sbb+   0); SSTEP(sbb+ 256);
      SSTEP(sbb+ 512); SSTEP(sbb+ 768);
      SSTEP(sbb+1024); SSTEP(sbb+1280);
      SSTEP(sbb+1536); SSTEP(sbb+1792);
    }
  }

  // ---- group 94: diags 753..760 (slot 2) ----
  WAITV(8);
  {
    const int gb = 2*2048;
    CSTEP_AB(gb+   0); CSTEP_BA(gb+ 256);
    CSTEP_AB(gb+ 512); CSTEP_BA(gb+ 768);
    CSTEP_AB(gb+1024); CSTEP_BA(gb+1280);
    CSTEP_AB(gb+1536); CSTEP_BA(gb+1792);
  }
  // ---- group 95: diags 761..766 (slot 3, 6 steps; 767/768 junk unused) ----
  WAITV(0);
  {
    const int gb = 3*2048;
    CSTEP_AB(gb+   0); CSTEP_BA(gb+ 256);
    CSTEP_AB(gb+ 512); CSTEP_BA(gb+ 768);
    CSTEP_AB(gb+1024); CSTEP_BA(gb+1280);
  }

  if (lane == 63) partial[b] = a5;   // D[383][383] (diag 766 even -> A set)

#undef CSTEP_AB
#undef CSTEP_BA
#undef BODYP
#undef WAITV
#undef SSTEP
#undef ADVX
}

// ---------------------------------------------------------------------------
// Kernel 3: mean of 128 partials -> out[0]
// ---------------------------------------------------------------------------
__global__ __launch_bounds__(64) void dtw_reduce(
    const float* __restrict__ partial, float* __restrict__ out)
{
  const int l = threadIdx.x;
  float v = partial[l] + partial[l + 64];
#pragma unroll
  for (int d = 32; d >= 1; d >>= 1) v += __shfl_xor(v, d, 64);
  if (l == 0) out[0] = v * (1.0f/128.0f);
}

extern "C" void kernel_launch(void* const* d_in, const int* in_sizes, int n_in,
                              void* d_out, int out_size, void* d_ws, size_t ws_size,
                              hipStream_t stream)
{
  (void)in_sizes; (void)n_in; (void)out_size; (void)ws_size;
  const float* s1 = (const float*)d_in[0];
  const float* s2 = (const float*)d_in[1];
  float* out = (float*)d_out;

  ushort* cost    = (ushort*)d_ws;                                     // 128*147840*2 B
  float*  partial = (float*)((char*)d_ws + (size_t)128*CB_STRIDE*2);   // 128 floats

  dtw_cost_gemm<<<dim3(9, 128), dim3(256), 0, stream>>>(s1, s2, cost);
  dtw_dp<<<dim3(128), dim3(64), 0, stream>>>(cost, partial);
  dtw_reduce<<<dim3(1), dim3(64), 0, stream>>>(partial, out);
}